// Round 15
// baseline (43.826 us; speedup 1.0000x reference)
//
#include <hip/hip_runtime.h>

// out[b] = sum_h [ dot(x1_bh,W1_h) + b1_h + dot(x2_bh,W2_h)
//                  + sum_o x2_bh[o] * dot(W3_h[o,:], x1_bh) ]
// B=16384, HEAD=8, DIM=128.
//
// R15: single regular kernel (R14's cooperative launch never executed under
// graph capture -> out==0). All cross-kernel structure removed WITHOUT grid
// sync:
//  - W3 split done IN-BLOCK: each block splits its head's 64KB fp32 W3
//    straight into LDS fragment order (bf16 hi/lo, 4 slots/thread). No prep
//    kernel, no ws round-trip (removes ~64MB of staging reads).
//  - Cross-head sum via atomicAdd into memset-zeroed out: 8 adds per sample,
//    device-scope by default; hipMemsetAsync each call -> no accumulation
//    across graph replays. No reduce kernel, no psum.
//  - Core = R13's VERIFIED mfma_f32_32x32x16_bf16 path (absmax 0.25), now
//    8 waves/block: 512 thr, 64KB LDS, 2 blocks/CU, grid 512 (64 sample
//    groups x 8 heads), head=bid&7 XCD-pinned.
// Layouts (m74/m101 HW-verified C/D): A: m=lane&31, k=(lane>>5)*8+j;
//   B: n=lane&31, same k (B[k][n]=W3[h][n][k]);
//   C/D: col=lane&31, row=(reg&3)+8*(reg>>2)+4*(lane>>5), reg in [0,16).
// Numerics: split-bf16 3-pass (hi*hi + lo*hi + hi*lo), t1 in exact fp32.

#define NB 16384
#define NHEAD 8
#define NDIM 128

typedef __attribute__((ext_vector_type(8))) short bf16x8;
typedef __attribute__((ext_vector_type(16))) float f32x16;

__global__ __launch_bounds__(512, 4) void bilinear_fused(
    const float* __restrict__ x1, const float* __restrict__ x2,
    const float* __restrict__ W1, const float* __restrict__ b1,
    const float* __restrict__ W2, const float* __restrict__ W3,
    float* __restrict__ out)
{
    const int tid = threadIdx.x;
    const int bid = blockIdx.x;
    const int w    = tid >> 6;
    const int l    = tid & 63;
    const int col  = l & 31;     // A-row m / B,C-col n
    const int hi5  = l >> 5;     // k-half; C-row group
    const int h    = bid & 7;    // head pinned per-XCD (round-robin)
    const int bw   = (bid >> 3) * 256 + w * 32;   // wave's 32 samples

    __shared__ short lhi[8][4][512];   // 32 KB: fragment order [ks][nt][lane*8]
    __shared__ short llo[8][4][512];   // 32 KB

    // ======== Phase A (in-block): split W3_h fp32 -> LDS bf16 frags ========
    // slot s in [0,2048): lane=s&63, nt=(s>>6)&3, ks=s>>8
    //   frag elem j: n = nt*32+(lane&31), k = ks*16+(lane>>5)*8+j
    // thread tid handles slots tid, tid+512, tid+1024, tid+1536
#pragma unroll
    for (int i = 0; i < 4; ++i) {
        const int s    = i * 512 + tid;
        const int lane = s & 63;
        const int nt   = (s >> 6) & 3;
        const int ks   = s >> 8;
        const int n    = nt * 32 + (lane & 31);
        const int k    = ks * 16 + (lane >> 5) * 8;
        const float* src = W3 + ((size_t)(h * NDIM + n)) * NDIM + k;
        const float4 a = *reinterpret_cast<const float4*>(src);
        const float4 b = *reinterpret_cast<const float4*>(src + 4);
        float xf[8] = {a.x, a.y, a.z, a.w, b.x, b.y, b.z, b.w};
        bf16x8 hi, lo;
#pragma unroll
        for (int j = 0; j < 8; ++j) {
            const unsigned u = __float_as_uint(xf[j]);
            hi[j] = (short)(u >> 16);
            const float hf = __uint_as_float(u & 0xffff0000u);
            lo[j] = (short)(__float_as_uint(xf[j] - hf) >> 16);
        }
        *reinterpret_cast<bf16x8*>(&lhi[ks][nt][lane * 8]) = hi;
        *reinterpret_cast<bf16x8*>(&llo[ks][nt][lane * 8]) = lo;
    }

    const float* __restrict__ w1base = W1 + h * NDIM;
    const float* __restrict__ x1row  = x1 + (size_t)(bw + col) * (NHEAD * NDIM)
                                          + h * NDIM + hi5 * 8;

    f32x16 acc[4];
#pragma unroll
    for (int nt = 0; nt < 4; ++nt) acc[nt] = (f32x16)0.f;
    float t1 = 0.f;

    __syncthreads();   // frags visible; the ONLY barrier

    // ======== Phase B: R13-verified 32x32x16 core ========
#pragma unroll
    for (int ks = 0; ks < 8; ++ks) {
        const int kbase = ks * 16;

        // A-fragment: 8 floats of x1, split in-register; t1 partial
        bf16x8 ahi, alo;
        {
            const float4 a = *reinterpret_cast<const float4*>(x1row + kbase);
            const float4 b = *reinterpret_cast<const float4*>(x1row + kbase + 4);
            float xf[8] = {a.x, a.y, a.z, a.w, b.x, b.y, b.z, b.w};
#pragma unroll
            for (int j = 0; j < 8; ++j) {
                const float w1l = w1base[kbase + j];         // uniform s_loads
                const float w1h = w1base[kbase + 8 + j];
                const unsigned u = __float_as_uint(xf[j]);
                ahi[j] = (short)(u >> 16);
                alo[j] = (short)(__float_as_uint(
                    xf[j] - __uint_as_float(u & 0xffff0000u)) >> 16);
                t1 += xf[j] * (hi5 ? w1h : w1l);
            }
        }

        // B-fragments from LDS (stride-1 b128, conflict-free), 3-pass
#pragma unroll
        for (int nt = 0; nt < 4; ++nt) {
            const bf16x8 bhi = *reinterpret_cast<const bf16x8*>(&lhi[ks][nt][l * 8]);
            const bf16x8 blo = *reinterpret_cast<const bf16x8*>(&llo[ks][nt][l * 8]);
            acc[nt] = __builtin_amdgcn_mfma_f32_32x32x16_bf16(ahi, bhi, acc[nt], 0, 0, 0);
            acc[nt] = __builtin_amdgcn_mfma_f32_32x32x16_bf16(alo, bhi, acc[nt], 0, 0, 0);
            acc[nt] = __builtin_amdgcn_mfma_f32_32x32x16_bf16(ahi, blo, acc[nt], 0, 0, 0);
        }
    }

    // ======== epilogue: cr[reg] = sum_o (P[row,o]+W2[o])*x2[row,o] ========
    float w2v[4];
#pragma unroll
    for (int nt = 0; nt < 4; ++nt) w2v[nt] = W2[h * NDIM + nt * 32 + col];

    float cr[16];
#pragma unroll
    for (int reg = 0; reg < 16; ++reg) {
        const int row = (reg & 3) + 8 * (reg >> 2) + 4 * hi5;
        const float* x2p = x2 + (size_t)(bw + row) * (NHEAD * NDIM)
                              + h * NDIM + col;
        float s = 0.f;
#pragma unroll
        for (int nt = 0; nt < 4; ++nt)
            s += (acc[nt][reg] + w2v[nt]) * x2p[nt * 32];
        cr[reg] = s;
    }
#pragma unroll
    for (int m = 1; m < 32; m <<= 1)
#pragma unroll
        for (int reg = 0; reg < 16; ++reg)
            cr[reg] += __shfl_xor(cr[reg], m, 64);

    float tf = t1;
    tf += __shfl_xor(tf, 32, 64);
#pragma unroll
    for (int reg = 0; reg < 16; ++reg) {
        const int row = (reg & 3) + 8 * (reg >> 2) + 4 * hi5;
        cr[reg] += __shfl(tf, row, 64);   // lane 'row' (<32) holds t1[row]
    }

    // writer: lanes col<16 own reg=col (static select, rule #20); one
    // atomicAdd per (head, sample) into memset-zeroed out; + b1[h] per head
    float outv = cr[0];
#pragma unroll
    for (int reg = 1; reg < 16; ++reg)
        if (col == reg) outv = cr[reg];
    if (col < 16) {
        const int row = (col & 3) + 8 * (col >> 2) + 4 * hi5;
        atomicAdd(&out[bw + row], outv + b1[h]);
    }
}

extern "C" void kernel_launch(void* const* d_in, const int* in_sizes, int n_in,
                              void* d_out, int out_size, void* d_ws, size_t ws_size,
                              hipStream_t stream) {
    const float* x1 = (const float*)d_in[0];
    const float* x2 = (const float*)d_in[1];
    const float* W1 = (const float*)d_in[2];
    const float* b1 = (const float*)d_in[3];
    const float* W2 = (const float*)d_in[4];
    const float* W3 = (const float*)d_in[5];
    float* out = (float*)d_out;

    hipMemsetAsync(out, 0, (size_t)NB * sizeof(float), stream);
    // 512 blocks (64 sample-groups x 8 heads) x 512 thr = 2 blocks/CU
    bilinear_fused<<<dim3(NB / 256 * NHEAD), dim3(512), 0, stream>>>(
        x1, x2, W1, b1, W2, W3, out);
}

// Round 16
// 37.976 us; speedup vs baseline: 1.1540x; 1.1540x over previous
//
#include <hip/hip_runtime.h>

// out[b] = sum_h [ dot(x1_bh,W1_h) + b1_h + dot(x2_bh,W2_h)
//                  + sum_o x2_bh[o] * dot(W3_h[o,:], x1_bh) ]
// B=16384, HEAD=8, DIM=128.
//
// R16: ONE kernel (+memset). R13's verified 32x32x16 core + geometry
// (grid 1024 = 128 sample-groups x 8 heads, 256 thr, 2-phase 32KB LDS,
// 4 blocks/CU) with:
//  - COALESCED in-block W3 split (fixes R15's scattered version): per phase,
//    thread loads 128B of W3_h fp32 LINEARLY (slot s = n*8+k8l -> consecutive
//    32B chunks), splits to bf16 hi/lo in-register, ds_write_b128 into the
//    verified fragment slots. No prep kernel, no ws staging traffic.
//  - atomicAdd epilogue (+b1[h]) into memset-zeroed out (proven R15):
//    no reduce kernel, no psum.
// Layouts (m74/m101 HW-verified C/D): A: m=lane&31, k=(lane>>5)*8+j;
//   B: n=lane&31, same k (B[k][n]=W3[h][n][k]);
//   C/D: col=lane&31, row=(reg&3)+8*(reg>>2)+4*(lane>>5), reg in [0,16).
// Numerics: split-bf16 3-pass (hi*hi + lo*hi + hi*lo), t1 in exact fp32.
// Fragment slot for (n,k): nt=n>>5, ks_local=((k>>4)&3), lane=((k>>3)&1)*32
//   + (n&31), elem j = k&7.

#define NB 16384
#define NHEAD 8
#define NDIM 128

typedef __attribute__((ext_vector_type(8))) short bf16x8;
typedef __attribute__((ext_vector_type(16))) float f32x16;

__global__ __launch_bounds__(256, 4) void bilinear_fused(
    const float* __restrict__ x1, const float* __restrict__ x2,
    const float* __restrict__ W1, const float* __restrict__ b1,
    const float* __restrict__ W2, const float* __restrict__ W3,
    float* __restrict__ out)
{
    const int tid  = threadIdx.x;
    const int l    = tid & 63;
    const int col  = l & 31;     // A-row m / B,C-col n
    const int hi5  = l >> 5;     // k-half; C-row group
    const int bid  = blockIdx.x;
    const int h    = bid & 7;    // head pinned per-XCD (round-robin)
    const int bw   = (bid >> 3) * 128 + (tid >> 6) * 32;  // wave's 32 samples

    __shared__ short lhi[4][4][512];   // 16 KB: one phase (4 ksteps)
    __shared__ short llo[4][4][512];   // 16 KB

    const float* __restrict__ w3base = W3 + (size_t)h * NDIM * NDIM;
    const float* __restrict__ w1base = W1 + h * NDIM;
    const float* __restrict__ x1row  = x1 + (size_t)(bw + col) * (NHEAD * NDIM)
                                          + h * NDIM + hi5 * 8;

    f32x16 acc[4];
#pragma unroll
    for (int nt = 0; nt < 4; ++nt) acc[nt] = (f32x16)0.f;
    float t1 = 0.f;

    for (int p = 0; p < 2; ++p) {
        // ---- in-block split, phase p: k-range [p*64, p*64+64) ----
        // slot s in [0,1024): n = s>>3, k8l = s&7, k = p*64 + k8l*8
        // src addr = (n*128 + k)*4 = n*512 + p*256 + k8l*32  (linear in s)
#pragma unroll
        for (int i = 0; i < 4; ++i) {
            const int s   = i * 256 + tid;
            const int n   = s >> 3;
            const int k8l = s & 7;
            const float* src = w3base + (size_t)n * NDIM + p * 64 + k8l * 8;
            const float4 a = *reinterpret_cast<const float4*>(src);
            const float4 b = *reinterpret_cast<const float4*>(src + 4);
            float xf[8] = {a.x, a.y, a.z, a.w, b.x, b.y, b.z, b.w};
            bf16x8 hi, lo;
#pragma unroll
            for (int j = 0; j < 8; ++j) {
                const unsigned u = __float_as_uint(xf[j]);
                hi[j] = (short)(u >> 16);
                const float hf = __uint_as_float(u & 0xffff0000u);
                lo[j] = (short)(__float_as_uint(xf[j] - hf) >> 16);
            }
            const int ksl  = k8l >> 1;                  // k-step within phase
            const int lane = (k8l & 1) * 32 + (n & 31); // frag lane
            const int nt   = n >> 5;
            *reinterpret_cast<bf16x8*>(&lhi[ksl][nt][lane * 8]) = hi;
            *reinterpret_cast<bf16x8*>(&llo[ksl][nt][lane * 8]) = lo;
        }
        __syncthreads();   // fragments visible

        // ---- compute 4 k-steps from this phase's slab ----
#pragma unroll
        for (int ksl = 0; ksl < 4; ++ksl) {
            const int kbase = p * 64 + ksl * 16;

            // A-fragment: 8 floats of x1, split in-register; t1 partial
            bf16x8 ahi, alo;
            {
                const float4 a = *reinterpret_cast<const float4*>(x1row + kbase);
                const float4 b = *reinterpret_cast<const float4*>(x1row + kbase + 4);
                float xf[8] = {a.x, a.y, a.z, a.w, b.x, b.y, b.z, b.w};
#pragma unroll
                for (int j = 0; j < 8; ++j) {
                    const float w1l = w1base[kbase + j];       // uniform
                    const float w1h = w1base[kbase + 8 + j];
                    const unsigned u = __float_as_uint(xf[j]);
                    ahi[j] = (short)(u >> 16);
                    alo[j] = (short)(__float_as_uint(
                        xf[j] - __uint_as_float(u & 0xffff0000u)) >> 16);
                    t1 += xf[j] * (hi5 ? w1h : w1l);
                }
            }

            // B-fragments from LDS (stride-1 b128, conflict-free), 3-pass
#pragma unroll
            for (int nt = 0; nt < 4; ++nt) {
                const bf16x8 bhi = *reinterpret_cast<const bf16x8*>(&lhi[ksl][nt][l * 8]);
                const bf16x8 blo = *reinterpret_cast<const bf16x8*>(&llo[ksl][nt][l * 8]);
                acc[nt] = __builtin_amdgcn_mfma_f32_32x32x16_bf16(ahi, bhi, acc[nt], 0, 0, 0);
                acc[nt] = __builtin_amdgcn_mfma_f32_32x32x16_bf16(alo, bhi, acc[nt], 0, 0, 0);
                acc[nt] = __builtin_amdgcn_mfma_f32_32x32x16_bf16(ahi, blo, acc[nt], 0, 0, 0);
            }
        }
        if (p == 0) __syncthreads();   // reads done before restage
    }

    // ---- epilogue: cr[reg] = sum_o (P[row,o]+W2[o])*x2[row,o] ----
    float w2v[4];
#pragma unroll
    for (int nt = 0; nt < 4; ++nt) w2v[nt] = W2[h * NDIM + nt * 32 + col];

    float cr[16];
#pragma unroll
    for (int reg = 0; reg < 16; ++reg) {
        const int row = (reg & 3) + 8 * (reg >> 2) + 4 * hi5;
        const float* x2p = x2 + (size_t)(bw + row) * (NHEAD * NDIM)
                              + h * NDIM + col;
        float s = 0.f;
#pragma unroll
        for (int nt = 0; nt < 4; ++nt)
            s += (acc[nt][reg] + w2v[nt]) * x2p[nt * 32];
        cr[reg] = s;
    }
#pragma unroll
    for (int m = 1; m < 32; m <<= 1)
#pragma unroll
        for (int reg = 0; reg < 16; ++reg)
            cr[reg] += __shfl_xor(cr[reg], m, 64);

    float tf = t1;
    tf += __shfl_xor(tf, 32, 64);
#pragma unroll
    for (int reg = 0; reg < 16; ++reg) {
        const int row = (reg & 3) + 8 * (reg >> 2) + 4 * hi5;
        cr[reg] += __shfl(tf, row, 64);   // lane 'row' (<32) holds t1[row]
    }

    // writer: lanes col<16 own reg=col (static select); one atomicAdd per
    // (head, sample) into memset-zeroed out; +b1[h] folded per head
    float outv = cr[0];
#pragma unroll
    for (int reg = 1; reg < 16; ++reg)
        if (col == reg) outv = cr[reg];
    if (col < 16) {
        const int row = (col & 3) + 8 * (col >> 2) + 4 * hi5;
        atomicAdd(&out[bw + row], outv + b1[h]);
    }
}

extern "C" void kernel_launch(void* const* d_in, const int* in_sizes, int n_in,
                              void* d_out, int out_size, void* d_ws, size_t ws_size,
                              hipStream_t stream) {
    const float* x1 = (const float*)d_in[0];
    const float* x2 = (const float*)d_in[1];
    const float* W1 = (const float*)d_in[2];
    const float* b1 = (const float*)d_in[3];
    const float* W2 = (const float*)d_in[4];
    const float* W3 = (const float*)d_in[5];
    float* out = (float*)d_out;

    hipMemsetAsync(out, 0, (size_t)NB * sizeof(float), stream);
    // 1024 blocks (128 sample-groups x 8 heads) x 256 thr = 4 blocks/CU
    bilinear_fused<<<dim3(NB / 128 * NHEAD), dim3(256), 0, stream>>>(
        x1, x2, W1, b1, W2, W3, out);
}